// Round 17
// baseline (642.419 us; speedup 1.0000x reference)
//
#include <hip/hip_runtime.h>
#include <hip/hip_bf16.h>

#define NB 4
#define SEQ 512
#define CIN 21
#define TDIM 4
#define DM 256
#define NH 8
#define PLEN 16
#define PSTR 8
#define EL 63
#define DFF 1024
#define PRED 96
#define NT 260
#define EPSV 1e-5f

// ---------------- helpers --------------------------------------------------
template<int R, int N>
__device__ __forceinline__ void dot_rows(const float* sx, int stride, const float* w, float* acc) {
  const float4* w4 = reinterpret_cast<const float4*>(w);
  #pragma unroll 4
  for (int i = 0; i < N / 4; ++i) {
    float4 c = w4[i];
    #pragma unroll
    for (int r = 0; r < R; ++r) {
      const float4* x4 = reinterpret_cast<const float4*>(sx + r * stride + i * 4);
      float4 a = *x4;
      acc[r] += a.x*c.x + a.y*c.y + a.z*c.z + a.w*c.w;
    }
  }
}

__device__ __forceinline__ float red32(float v) {
  #pragma unroll
  for (int m = 1; m < 32; m <<= 1) v += __shfl_xor(v, m, 64);
  return v;
}
__device__ __forceinline__ float red32max(float v) {
  #pragma unroll
  for (int m = 1; m < 32; m <<= 1) v = fmaxf(v, __shfl_xor(v, m, 64));
  return v;
}

__device__ __forceinline__ float2 meanvar256(float v, float* sb) {
  __syncthreads();
  float s1 = v, s2 = v * v;
  #pragma unroll
  for (int off = 32; off > 0; off >>= 1) {
    s1 += __shfl_down(s1, off, 64);
    s2 += __shfl_down(s2, off, 64);
  }
  int wid = threadIdx.x >> 6, lane = threadIdx.x & 63;
  if (lane == 0) { sb[wid * 2] = s1; sb[wid * 2 + 1] = s2; }
  __syncthreads();
  float m = (sb[0] + sb[2] + sb[4] + sb[6]) * (1.0f / 256.0f);
  float q = (sb[1] + sb[3] + sb[5] + sb[7]) * (1.0f / 256.0f);
  return make_float2(m, q - m * m);
}

__device__ __forceinline__ void load16f(const float* p, float* o) {
  const float4* q = reinterpret_cast<const float4*>(p);
  float4 a = q[0], b = q[1], c = q[2], d = q[3];
  o[0]=a.x; o[1]=a.y; o[2]=a.z; o[3]=a.w;
  o[4]=b.x; o[5]=b.y; o[6]=b.z; o[7]=b.w;
  o[8]=c.x; o[9]=c.y; o[10]=c.z; o[11]=c.w;
  o[12]=d.x; o[13]=d.y; o[14]=d.z; o[15]=d.w;
}

__device__ __forceinline__ float dot32(const float4* a, const float4* b) {
  float s = 0.f;
  #pragma unroll
  for (int i = 0; i < 8; ++i) {
    float4 x = a[i], y = b[i];
    s += x.x*y.x + x.y*y.y + x.z*y.z + x.w*y.w;
  }
  return s;
}

// ---- K1: fused RevIN stats (84 blocks) + patch-time means (4 blocks) -----
__global__ void k_stats(const float* __restrict__ x, const float* __restrict__ xm,
                        float* __restrict__ means, float* __restrict__ stdev,
                        float* __restrict__ tout) {
  int blk = blockIdx.x;
  int t = threadIdx.x;
  if (blk < NB * CIN) {
    int b = blk / CIN, c = blk % CIN;
    const float* p = x + (size_t)b * SEQ * CIN + c;
    float v0 = p[t * CIN];
    float v1 = p[(t + 256) * CIN];
    float s1 = v0 + v1, s2 = v0 * v0 + v1 * v1;
    __shared__ float sb[8];
    #pragma unroll
    for (int off = 32; off > 0; off >>= 1) {
      s1 += __shfl_down(s1, off, 64);
      s2 += __shfl_down(s2, off, 64);
    }
    int wid = t >> 6, lane = t & 63;
    if (lane == 0) { sb[wid * 2] = s1; sb[wid * 2 + 1] = s2; }
    __syncthreads();
    if (t == 0) {
      float a = sb[0] + sb[2] + sb[4] + sb[6];
      float q = sb[1] + sb[3] + sb[5] + sb[7];
      float m = a * (1.0f / 512.0f);
      float var = q * (1.0f / 512.0f) - m * m;
      means[blk] = m;
      stdev[blk] = sqrtf(var + EPSV);
    }
  } else {
    int idx = (blk - NB * CIN) * 256 + t;
    if (idx >= NB * EL * TDIM) return;
    int b = idx / (EL * TDIM), r = idx % (EL * TDIM);
    int l = r >> 2, ti = r & 3;
    const float* p = xm + (size_t)b * SEQ * TDIM + (size_t)l * PSTR * TDIM + ti;
    float s = 0.f;
    #pragma unroll
    for (int k = 0; k < PLEN; ++k) s += p[k * TDIM];
    tout[idx] = s * (1.f / 16.f);
  }
}

// ---- K3a: token conv + PE, 8 positions per block -------------------------
__global__ void __launch_bounds__(256) k_tokconv(
    const float* __restrict__ x, const float* __restrict__ tokW,
    const float* __restrict__ means, const float* __restrict__ stdev,
    float* __restrict__ enc1) {
  int bi = blockIdx.x;                       // b*64 + sg
  int b = bi >> 6, sg = bi & 63;
  int s0 = sg * 8;
  __shared__ float sxr[10 * CIN];
  int t = threadIdx.x;
  if (t < 10 * CIN) {
    int li = t / CIN, c = t % CIN;
    int row = (s0 - 1 + li + SEQ) & 511;
    sxr[t] = (x[(size_t)b * SEQ * CIN + row * CIN + c] - means[b * CIN + c])
             / stdev[b * CIN + c];
  }
  __syncthreads();
  int d = t;
  float wreg[63];
  #pragma unroll
  for (int q = 0; q < 63; ++q) wreg[q] = tokW[d * 63 + q];
  int de = d & ~1;
  float dv = expf((float)de * (-9.210340371976184f / 256.0f));
  bool isodd = (d & 1);
  #pragma unroll 1
  for (int k = 0; k < 8; ++k) {
    float acc = 0.f;
    const float* sr = sxr + k * CIN;
    #pragma unroll
    for (int c = 0; c < CIN; ++c) {
      acc += sr[c]           * wreg[c * 3 + 0];
      acc += sr[CIN + c]     * wreg[c * 3 + 1];
      acc += sr[2 * CIN + c] * wreg[c * 3 + 2];
    }
    float ang = (float)(s0 + k) * dv;
    float pe = isodd ? cosf(ang) : sinf(ang);
    enc1[((size_t)b * SEQ + s0 + k) * DM + d] = acc + pe;
  }
}

// ---- K3b: patch conv partials, 6 patches x 32-channel chunk per block ----
__global__ void __launch_bounds__(256) k_patch_part(
    const float* __restrict__ enc1, const float* __restrict__ pW,
    float* __restrict__ pbuf) {
  int bi = blockIdx.x;
  int pg = bi >> 3, kc = bi & 7;
  int p0 = pg * 6;
  __shared__ __align__(16) float sA[6 * 32 * 20];
  int t = threadIdx.x;
  for (int idx = t; idx < 6 * 32 * PLEN; idx += 256) {
    int pp = idx >> 9;
    int rem = idx & 511;
    int c = rem >> 4, k = rem & 15;
    int p = p0 + pp;
    int b = p / EL, l = p % EL;
    sA[pp * 640 + c * 20 + k] =
        enc1[((size_t)b * SEQ + l * PSTR + k) * DM + kc * 32 + c];
  }
  __syncthreads();
  int d = t;
  const float4* w4 = reinterpret_cast<const float4*>(
      pW + (size_t)d * (DM * PLEN) + kc * 32 * PLEN);
  float acc[6] = {0.f, 0.f, 0.f, 0.f, 0.f, 0.f};
  #pragma unroll 2
  for (int c = 0; c < 32; ++c) {
    float4 w0 = w4[c*4+0], w1 = w4[c*4+1], w2 = w4[c*4+2], w3 = w4[c*4+3];
    #pragma unroll
    for (int pp = 0; pp < 6; ++pp) {
      const float4* px = reinterpret_cast<const float4*>(sA + pp * 640 + c * 20);
      float4 x0 = px[0], x1 = px[1], x2 = px[2], x3 = px[3];
      acc[pp] += x0.x*w0.x + x0.y*w0.y + x0.z*w0.z + x0.w*w0.w
               + x1.x*w1.x + x1.y*w1.y + x1.z*w1.z + x1.w*w1.w
               + x2.x*w2.x + x2.y*w2.y + x2.z*w2.z + x2.w*w2.w
               + x3.x*w3.x + x3.y*w3.y + x3.z*w3.z + x3.w*w3.w;
    }
  }
  const int S = NB * EL * DM;
  #pragma unroll
  for (int pp = 0; pp < 6; ++pp)
    pbuf[(size_t)kc * S + (size_t)(p0 + pp) * DM + d] = acc[pp];
}

// ---- K3c: reduce partials + bias -----------------------------------------
__global__ void k_patch_red(const float* __restrict__ pbuf, const float* __restrict__ pb,
                            float* __restrict__ encP) {
  int p = blockIdx.x, t = threadIdx.x;
  const int S = NB * EL * DM;
  float v = 0.f;
  #pragma unroll
  for (int s = 0; s < 8; ++s) v += pbuf[(size_t)s * S + (size_t)p * DM + t];
  encP[(size_t)p * DM + t] = v + pb[t];
}

// ---- QKV: one matrix per block, R rows, LDS-staged -----------------------
template<int R>
__global__ void __launch_bounds__(256) k_qkv1(
    const float* __restrict__ Wq, const float* __restrict__ Wk,
    const float* __restrict__ Wv,
    const float* __restrict__ bq, const float* __restrict__ bk,
    const float* __restrict__ bv,
    const float* __restrict__ xin,
    float* __restrict__ qo, float* __restrict__ ko, float* __restrict__ vo) {
  int bi = blockIdx.x;
  int rg = bi / 3, mat = bi % 3;
  int row0 = rg * R;
  __shared__ __align__(16) float sx[R * DM];
  int t = threadIdx.x;
  for (int idx = t; idx < R * DM; idx += 256) sx[idx] = xin[(size_t)row0 * DM + idx];
  __syncthreads();
  const float* W = (mat == 0) ? Wq : (mat == 1) ? Wk : Wv;
  const float* bias = (mat == 0) ? bq : (mat == 1) ? bk : bv;
  float* out = (mat == 0) ? qo : (mat == 1) ? ko : vo;
  float acc[R];
  #pragma unroll
  for (int r = 0; r < R; ++r) acc[r] = 0.f;
  dot_rows<R, DM>(sx, DM, W + (size_t)t * DM, acc);
  float bv_ = bias ? bias[t] : 0.f;
  #pragma unroll
  for (int r = 0; r < R; ++r) out[(size_t)(row0 + r) * DM + t] = acc[r] + bv_;
}

// ---- g_rel + g_abs(gi) precompute, BOTH layers in one launch -------------
__global__ void __launch_bounds__(256) k_grel2(
    const float* __restrict__ tws,
    const float* __restrict__ mu_r, const float* __restrict__ sg_r,
    const float* __restrict__ w_r,
    const float* __restrict__ mu_a, const float* __restrict__ sg_a,
    const float* __restrict__ w_a,
    float* __restrict__ grel, float* __restrict__ gib) {
  int blk = blockIdx.x;                      // L*(NB*252) + b*252 + chunk
  int L = blk / (NB * 252);
  int rem0 = blk % (NB * 252);
  int b = rem0 / 252, chunk = rem0 % 252;
  int po = L * 4096;
  float* grelL = grel + (size_t)L * (NB * NH * EL * EL);
  float* gibL  = gib + (size_t)L * (NB * NH * EL);
  int t = threadIdx.x;
  int h = t >> 5, dh = t & 31;
  __shared__ float s_t[EL * TDIM];
  if (t < EL * TDIM) s_t[t] = tws[b * EL * TDIM + t];
  float pm[16], pc[16], pw[16];
  load16f(mu_r + po + (size_t)t * 16, pm);
  load16f(sg_r + po + (size_t)t * 16, pc);
  load16f(w_r  + po + (size_t)t * 16, pw);
  #pragma unroll
  for (int p = 0; p < 16; ++p) pc[p] = -0.5f / (pc[p] * pc[p]);
  __syncthreads();
  #pragma unroll 1
  for (int q = 0; q < 8; ++q) {
    int p = chunk * 8 + q;                   // 2016 (i<=j) pairs
    int i = (int)((127.0f - sqrtf(16129.0f - 8.0f * (float)p)) * 0.5f);
    while (i * (127 - i) / 2 > p) --i;
    while ((i + 1) * (126 - i) / 2 <= p) ++i;
    int j = i + (p - i * (127 - i) / 2);
    float dvv[4];
    dvv[0] = fabsf(s_t[i*4+0] - s_t[j*4+0]);
    dvv[1] = fabsf(s_t[i*4+1] - s_t[j*4+1]);
    dvv[2] = fabsf(s_t[i*4+2] - s_t[j*4+2]);
    dvv[3] = fabsf(s_t[i*4+3] - s_t[j*4+3]);
    float srel = 0.f;
    #pragma unroll
    for (int tt = 0; tt < 4; ++tt)
      #pragma unroll
      for (int k = 0; k < 4; ++k) {
        int pp = tt * 4 + k;
        float df = dvv[tt] - pm[pp];
        srel += pw[pp] * __expf(pc[pp] * df * df);
      }
    #pragma unroll
    for (int m = 1; m < 32; m <<= 1) srel += __shfl_xor(srel, m, 64);
    if (dh == 0) {
      float v = srel * (1.f / 32.f);
      grelL[(((size_t)b * NH + h) * EL + i) * EL + j] = v;
      grelL[(((size_t)b * NH + h) * EL + j) * EL + i] = v;
    }
  }
  if (chunk < EL) {
    load16f(mu_a + po + (size_t)t * 16, pm);
    load16f(sg_a + po + (size_t)t * 16, pc);
    load16f(w_a  + po + (size_t)t * 16, pw);
    #pragma unroll
    for (int p = 0; p < 16; ++p) pc[p] = -0.5f / (pc[p] * pc[p]);
    int i = chunk;
    float tiv[4] = {s_t[i*4+0], s_t[i*4+1], s_t[i*4+2], s_t[i*4+3]};
    float sabs = 0.f;
    #pragma unroll
    for (int tt = 0; tt < 4; ++tt)
      #pragma unroll
      for (int k = 0; k < 4; ++k) {
        int pp = tt * 4 + k;
        float df = tiv[tt] - pm[pp];
        sabs += pw[pp] * __expf(pc[pp] * df * df);
      }
    #pragma unroll
    for (int m = 1; m < 32; m <<= 1) sabs += __shfl_xor(sabs, m, 64);
    if (dh == 0) gibL[((size_t)b * NH + h) * EL + i] = sabs * (1.f / 32.f);
  }
}

// ---- TKA attention: register-dot scores, no lane reductions --------------
__global__ void __launch_bounds__(256) k_tka_attn(
    const float* __restrict__ xin, const float* __restrict__ qw,
    const float* __restrict__ kw, const float* __restrict__ vw,
    const float* __restrict__ grel, const float* __restrict__ gib,
    const float* __restrict__ alpha, const float* __restrict__ beta,
    const float* __restrict__ gamma, float* __restrict__ ao) {
  int bi = blockIdx.x;                       // b*63+i
  int b = bi / EL, i = bi % EL;
  int t = threadIdx.x;
  int h = t >> 5, jj = t & 31;
  __shared__ __align__(16) float sQX[2 * DM];
  __shared__ float sP[NH * 64];
  if (t < DM) {
    sQX[t] = qw[(size_t)bi * DM + t];
    sQX[DM + t] = xin[(size_t)bi * DM + t];
  }
  __syncthreads();
  float gi = gib[((size_t)b * NH + h) * EL + i];
  float al = alpha[h], be = beta[h], ga = gamma[h];
  const float scale = 0.17677669529663687f;
  const float* grow = grel + (((size_t)b * NH + h) * EL + i) * EL;

  #pragma unroll
  for (int tile = 0; tile < 2; ++tile) {
    int j = tile * 32 + jj;
    bool valid = (j < EL);
    int jc = valid ? j : (EL - 1);
    const float4* kp = reinterpret_cast<const float4*>(
        kw + (size_t)(b * EL + jc) * DM + h * 32);
    const float4* xp = reinterpret_cast<const float4*>(
        xin + (size_t)(b * EL + jc) * DM + h * 32);
    float4 kf[8], xf[8];
    #pragma unroll
    for (int q = 0; q < 8; ++q) { kf[q] = kp[q]; xf[q] = xp[q]; }
    float qk  = dot32(reinterpret_cast<const float4*>(sQX + h * 32), kf);
    float pij = dot32(reinterpret_cast<const float4*>(sQX + DM + h * 32), xf);
    float A = al * pij * (2.f * gi) + be * pij * grow[jc] + ga;
    sP[h * 64 + tile * 32 + jj] = valid ? (qk * scale * A) : -1e30f;
  }
  __syncthreads();
  {
    int dh = jj;
    float v0 = sP[h * 64 + dh];
    float v1 = (dh + 32 < EL) ? sP[h * 64 + dh + 32] : -1e30f;
    float m = red32max(fmaxf(v0, v1));
    float e0 = __expf(v0 - m);
    float e1 = (dh + 32 < EL) ? __expf(v1 - m) : 0.f;
    float s = red32(e0 + e1);
    float inv = 1.f / s;
    sP[h * 64 + dh] = e0 * inv;
    if (dh + 32 < EL) sP[h * 64 + dh + 32] = e1 * inv;
  }
  __syncthreads();
  float acc = 0.f;
  for (int j = 0; j < EL; ++j)
    acc += sP[h * 64 + j] * vw[(size_t)(b * EL + j) * DM + t];
  ao[(size_t)bi * DM + t] = acc;
}

// ---- output projection (no LN), R rows, LDS-staged -----------------------
template<int R>
__global__ void k_oproj(const float* __restrict__ Wo, const float* __restrict__ bo,
                        const float* __restrict__ ain, float* __restrict__ out) {
  int row0 = blockIdx.x * R;
  __shared__ __align__(16) float sx[R * DM];
  int t = threadIdx.x;
  for (int idx = t; idx < R * DM; idx += 256) sx[idx] = ain[(size_t)row0 * DM + idx];
  __syncthreads();
  float acc[R];
  #pragma unroll
  for (int r = 0; r < R; ++r) acc[r] = 0.f;
  dot_rows<R, DM>(sx, DM, Wo + (size_t)t * DM, acc);
  float bias = bo[t];
  #pragma unroll
  for (int r = 0; r < R; ++r) out[(size_t)(row0 + r) * DM + t] = acc[r] + bias;
}

// ---- inverted embedding ----------------------------------------------------
__global__ void k_invemb(const float* __restrict__ invW, const float* __restrict__ invb,
                         const float* __restrict__ encP, const float* __restrict__ tws,
                         float* __restrict__ enc2) {
  int bi = blockIdx.x;                       // b*260+n
  int b = bi / NT, n = bi % NT;
  __shared__ float sx[EL];
  int t = threadIdx.x;
  if (t < EL) {
    sx[t] = (n < DM) ? encP[(size_t)(b * EL + t) * DM + n]
                     : tws[b * EL * TDIM + t * TDIM + (n - DM)];
  }
  __syncthreads();
  const float* w = invW + (size_t)t * EL;
  float acc = 0.f;
  for (int l = 0; l < EL; ++l) acc += sx[l] * w[l];
  enc2[(size_t)bi * DM + t] = acc + invb[t];
}

// ---- encoder attention: two-pass, full S in LDS --------------------------
__global__ void __launch_bounds__(256) k_enc_attn(
    const float* __restrict__ qw, const float* __restrict__ kw,
    const float* __restrict__ vw, float* __restrict__ ao) {
  int blk = blockIdx.x;                      // b*65 + tile
  int b = blk / 65, it = blk % 65;
  int i0 = it * 4;
  int t = threadIdx.x;
  int h = t >> 5, jj = t & 31;

  __shared__ __align__(16) float sQ[4 * DM];
  __shared__ float sS[4 * NH * NT];          // 33.3 KB
  __shared__ float sL[4 * NH];

  for (int idx = t; idx < 4 * DM; idx += 256)
    sQ[idx] = qw[((size_t)(b * NT + i0)) * DM + idx];
  __syncthreads();

  const float scale = 0.17677669529663687f;
  for (int tile = 0; tile < 9; ++tile) {
    int j = tile * 32 + jj;
    if (j >= NT) break;
    const float4* kp = reinterpret_cast<const float4*>(
        kw + ((size_t)(b * NT + j)) * DM + h * 32);
    float4 kf[8];
    #pragma unroll
    for (int q = 0; q < 8; ++q) kf[q] = kp[q];
    #pragma unroll
    for (int i = 0; i < 4; ++i) {
      float s = dot32(reinterpret_cast<const float4*>(sQ + i * DM + h * 32), kf);
      sS[(i * NH + h) * NT + j] = s * scale;
    }
  }
  __syncthreads();
  {
    int combo = t >> 3, lane8 = t & 7;
    float* row = sS + (size_t)combo * NT;
    float m = -1e30f;
    for (int jx = lane8; jx < NT; jx += 8) m = fmaxf(m, row[jx]);
    #pragma unroll
    for (int s8 = 1; s8 < 8; s8 <<= 1) m = fmaxf(m, __shfl_xor(m, s8, 64));
    float ssum = 0.f;
    for (int jx = lane8; jx < NT; jx += 8) {
      float e = __expf(row[jx] - m);
      row[jx] = e;
      ssum += e;
    }
    #pragma unroll
    for (int s8 = 1; s8 < 8; s8 <<= 1) ssum += __shfl_xor(ssum, s8, 64);
    if (lane8 == 0) sL[combo] = ssum;
  }
  __syncthreads();
  {
    int ch = t, hh = ch >> 5;
    float o0 = 0.f, o1 = 0.f, o2 = 0.f, o3 = 0.f;
    const float* vbase = vw + ((size_t)(b * NT)) * DM + ch;
    const float* p0 = sS + (0 * NH + hh) * NT;
    const float* p1 = sS + (1 * NH + hh) * NT;
    const float* p2 = sS + (2 * NH + hh) * NT;
    const float* p3 = sS + (3 * NH + hh) * NT;
    for (int j = 0; j < NT; ++j) {
      float v = vbase[(size_t)j * DM];
      o0 += p0[j] * v; o1 += p1[j] * v; o2 += p2[j] * v; o3 += p3[j] * v;
    }
    size_t obase = ((size_t)(b * NT + i0)) * DM + ch;
    ao[obase + 0 * DM] = o0 / sL[0 * NH + hh];
    ao[obase + 1 * DM] = o1 / sL[1 * NH + hh];
    ao[obase + 2 * DM] = o2 / sL[2 * NH + hh];
    ao[obase + 3 * DM] = o3 / sL[3 * NH + hh];
  }
}

// ---- Wo proj + residual + LN, 4 rows, LDS-staged -------------------------
__global__ void __launch_bounds__(256) k_oproj_res_ln(
    const float* __restrict__ Wo, const float* __restrict__ bo,
    const float* __restrict__ g, const float* __restrict__ bb,
    const float* __restrict__ ain, const float* __restrict__ resin,
    float* __restrict__ out) {
  int row0 = blockIdx.x * 4;
  __shared__ __align__(16) float sx[4 * DM];
  __shared__ float sb[8];
  int t = threadIdx.x;
  for (int idx = t; idx < 4 * DM; idx += 256) sx[idx] = ain[(size_t)row0 * DM + idx];
  __syncthreads();
  float acc[4] = {0.f, 0.f, 0.f, 0.f};
  dot_rows<4, DM>(sx, DM, Wo + (size_t)t * DM, acc);
  float bias = bo[t], gg = g[t], bb2 = bb[t];
  #pragma unroll 1
  for (int r = 0; r < 4; ++r) {
    float o = acc[r] + bias + resin[(size_t)(row0 + r) * DM + t];
    float2 mv = meanvar256(o, sb);
    out[(size_t)(row0 + r) * DM + t] = (o - mv.x) * rsqrtf(mv.y + EPSV) * gg + bb2;
  }
}

// ---- FFN1: gelu(x@W1.T+b1), 4 rows x 256 f per block ---------------------
__global__ void __launch_bounds__(256) k_ffn1(
    const float* __restrict__ W1, const float* __restrict__ b1,
    const float* __restrict__ xn, float* __restrict__ y1) {
  int bi = blockIdx.x;                       // rg*4 + fg
  int rg = bi >> 2, fg = bi & 3;
  int row0 = rg * 4;
  __shared__ __align__(16) float sx[4 * DM];
  int t = threadIdx.x;
  for (int idx = t; idx < 4 * DM; idx += 256) sx[idx] = xn[(size_t)row0 * DM + idx];
  __syncthreads();
  int f = fg * 256 + t;
  float acc[4] = {0.f, 0.f, 0.f, 0.f};
  dot_rows<4, DM>(sx, DM, W1 + (size_t)f * DM, acc);
  float bias = b1[f];
  #pragma unroll
  for (int r = 0; r < 4; ++r) {
    float a = acc[r] + bias;
    y1[(size_t)(row0 + r) * DFF + f] = 0.5f * a * (1.f + erff(a * 0.70710678118654752f));
  }
}

// ---- FFN2 partials: 4 rows x 256-K chunk per block -----------------------
__global__ void __launch_bounds__(256) k_ffn2_part(
    const float* __restrict__ W2, const float* __restrict__ y1,
    float* __restrict__ fbuf) {
  int bi = blockIdx.x;                       // rg*4 + kc
  int rg = bi >> 2, kc = bi & 3;
  int row0 = rg * 4;
  __shared__ __align__(16) float sy[4 * 256];
  int t = threadIdx.x;
  for (int idx = t; idx < 4 * 256; idx += 256) {
    int r = idx >> 8, k = idx & 255;
    sy[idx] = y1[(size_t)(row0 + r) * DFF + kc * 256 + k];
  }
  __syncthreads();
  float acc[4] = {0.f, 0.f, 0.f, 0.f};
  dot_rows<4, 256>(sy, 256, W2 + (size_t)t * DFF + kc * 256, acc);
  const size_t S = (size_t)NB * NT * DM;
  #pragma unroll
  for (int r = 0; r < 4; ++r)
    fbuf[(size_t)kc * S + (size_t)(row0 + r) * DM + t] = acc[r];
}

// ---- FFN2 reduce + bias + residual + LN, 4 rows --------------------------
__global__ void __launch_bounds__(256) k_ffn2_red(
    const float* __restrict__ fbuf, const float* __restrict__ b2,
    const float* __restrict__ g, const float* __restrict__ bb,
    const float* __restrict__ xn, float* __restrict__ out) {
  int row0 = blockIdx.x * 4;
  __shared__ float sb[8];
  int t = threadIdx.x;
  const size_t S = (size_t)NB * NT * DM;
  float bi_ = b2[t], gg = g[t], bb2 = bb[t];
  #pragma unroll 1
  for (int r = 0; r < 4; ++r) {
    size_t off = (size_t)(row0 + r) * DM + t;
    float o = fbuf[off] + fbuf[S + off] + fbuf[2 * S + off] + fbuf[3 * S + off]
            + bi_ + xn[off];
    float2 mv = meanvar256(o, sb);
    out[off] = (o - mv.x) * rsqrtf(mv.y + EPSV) * gg + bb2;
  }
}

// ---- final LN + projection + denorm (fp32 output) ------------------------
__global__ void k_final(const float* __restrict__ g, const float* __restrict__ bb,
                        const float* __restrict__ pW, const float* __restrict__ pb,
                        const float* __restrict__ enc2,
                        const float* __restrict__ stdev, const float* __restrict__ means,
                        float* __restrict__ out) {
  int bi = blockIdx.x;                       // b*21+c
  int b = bi / CIN, c = bi % CIN;
  __shared__ __align__(16) float sx[DM];
  __shared__ float sb[8];
  int t = threadIdx.x;
  float v = enc2[(size_t)(b * NT + c) * DM + t];
  float2 mv = meanvar256(v, sb);
  sx[t] = (v - mv.x) * rsqrtf(mv.y + EPSV) * g[t] + bb[t];
  __syncthreads();
  if (t < PRED) {
    float acc[1] = {0.f};
    dot_rows<1, DM>(sx, DM, pW + (size_t)t * DM, acc);
    float y = (acc[0] + pb[t]) * stdev[bi] + means[bi];
    out[(size_t)b * PRED * CIN + t * CIN + c] = y;
  }
}

extern "C" void kernel_launch(void* const* d_in, const int* in_sizes, int n_in,
                              void* d_out, int out_size, void* d_ws, size_t ws_size,
                              hipStream_t stream) {
  const float* x_enc   = (const float*)d_in[0];
  const float* x_mark  = (const float*)d_in[1];
  const float* tok_W   = (const float*)d_in[4];
  const float* patch_W = (const float*)d_in[5];
  const float* patch_b = (const float*)d_in[6];
  const float* nl_WQ   = (const float*)d_in[7];
  const float* nl_WK   = (const float*)d_in[8];
  const float* nl_WV   = (const float*)d_in[9];
  const float* nl_WO   = (const float*)d_in[10];
  const float* nl_bO   = (const float*)d_in[11];
  const float* nl_mu_a = (const float*)d_in[12];
  const float* nl_sg_a = (const float*)d_in[13];
  const float* nl_w_a  = (const float*)d_in[14];
  const float* nl_mu_r = (const float*)d_in[15];
  const float* nl_sg_r = (const float*)d_in[16];
  const float* nl_w_r  = (const float*)d_in[17];
  const float* nl_al   = (const float*)d_in[18];
  const float* nl_be   = (const float*)d_in[19];
  const float* nl_ga   = (const float*)d_in[20];
  const float* inv_W   = (const float*)d_in[21];
  const float* inv_b   = (const float*)d_in[22];
  const float* el_Wq   = (const float*)d_in[23];
  const float* el_bq   = (const float*)d_in[24];
  const float* el_Wk   = (const float*)d_in[25];
  const float* el_bk   = (const float*)d_in[26];
  const float* el_Wv   = (const float*)d_in[27];
  const float* el_bv   = (const float*)d_in[28];
  const float* el_Wo   = (const float*)d_in[29];
  const float* el_bo   = (const float*)d_in[30];
  const float* el_W1   = (const float*)d_in[31];
  const float* el_b1   = (const float*)d_in[32];
  const float* el_W2   = (const float*)d_in[33];
  const float* el_b2   = (const float*)d_in[34];
  const float* n1g     = (const float*)d_in[35];
  const float* n1b     = (const float*)d_in[36];
  const float* n2g     = (const float*)d_in[37];
  const float* n2b     = (const float*)d_in[38];
  const float* norm_g  = (const float*)d_in[39];
  const float* norm_b  = (const float*)d_in[40];
  const float* proj_W  = (const float*)d_in[41];
  const float* proj_b  = (const float*)d_in[42];

  // workspace layout (floats): ~19.3 MB
  float* ws = (float*)d_ws;
  float* means = ws + 0;          //     96
  float* stdev = ws + 96;         //     96
  float* tws   = ws + 192;        //   1024
  float* enc1  = ws + 1216;       // 524288  (B,512,256)
  float* encP  = ws + 525504;     //  64512  (252,256)
  float* pbuf  = ws + 590016;     // 516096  (8,252,256)
  float* enc2  = ws + 1106112;    // 266240  (1040,256)
  float* ao    = ws + 1372352;    // 266240
  float* qb    = ws + 1638592;    // 266240  (xn aliases qb)
  float* kb    = ws + 1904832;    // 266240
  float* vb    = ws + 2171072;    // 266240
  float* y1    = ws + 2437312;    // 1064960 (1040,1024)
  float* fbuf  = ws + 3502272;    // 1064960 (4,1040,256)
  float* grel  = ws + 4567232;    // 254016  (2,B,8,63,63)
  float* gib   = ws + 4821248;    //   4032  (2,B,8,63)
  float* xn    = qb;              // alias: qb dead after k_enc_attn

  k_stats<<<NB * CIN + 4, 256, 0, stream>>>(x_enc, x_mark, means, stdev, tws);
  k_tokconv<<<NB * 64, 256, 0, stream>>>(x_enc, tok_W, means, stdev, enc1);
  k_grel2<<<2 * NB * 252, 256, 0, stream>>>(tws, nl_mu_r, nl_sg_r, nl_w_r,
                                            nl_mu_a, nl_sg_a, nl_w_a, grel, gib);
  k_patch_part<<<42 * 8, 256, 0, stream>>>(enc1, patch_W, pbuf);
  k_patch_red<<<NB * EL, 256, 0, stream>>>(pbuf, patch_b, encP);

  for (int L = 0; L < 2; ++L) {
    size_t wo = (size_t)L * DM * DM;
    k_qkv1<2><<<126 * 3, 256, 0, stream>>>(nl_WQ + wo, nl_WK + wo, nl_WV + wo,
                                           nullptr, nullptr, nullptr,
                                           encP, qb, kb, vb);
    k_tka_attn<<<NB * EL, 256, 0, stream>>>(encP, qb, kb, vb,
        grel + (size_t)L * (NB * NH * EL * EL), gib + (size_t)L * (NB * NH * EL),
        nl_al + L * 8, nl_be + L * 8, nl_ga + L * 8, ao);
    k_oproj<1><<<NB * EL, 256, 0, stream>>>(nl_WO + wo, nl_bO + L * DM, ao, encP);
  }

  k_invemb<<<NB * NT, 256, 0, stream>>>(inv_W, inv_b, encP, tws, enc2);

  for (int L = 0; L < 2; ++L) {
    size_t wo = (size_t)L * DM * DM;
    size_t bo = (size_t)L * DM;
    size_t fo = (size_t)L * DFF * DM;
    k_qkv1<4><<<260 * 3, 256, 0, stream>>>(el_Wq + wo, el_Wk + wo, el_Wv + wo,
                                           el_bq + bo, el_bk + bo, el_bv + bo,
                                           enc2, qb, kb, vb);
    k_enc_attn<<<NB * 65, 256, 0, stream>>>(qb, kb, vb, ao);
    k_oproj_res_ln<<<NB * NT / 4, 256, 0, stream>>>(el_Wo + wo, el_bo + bo,
                                                    n1g + bo, n1b + bo,
                                                    ao, enc2, xn);
    k_ffn1<<<260 * 4, 256, 0, stream>>>(el_W1 + fo, el_b1 + L * DFF, xn, y1);
    k_ffn2_part<<<260 * 4, 256, 0, stream>>>(el_W2 + fo, y1, fbuf);
    k_ffn2_red<<<NB * NT / 4, 256, 0, stream>>>(fbuf, el_b2 + bo,
                                                n2g + bo, n2b + bo, xn, enc2);
  }

  k_final<<<NB * CIN, 256, 0, stream>>>(norm_g, norm_b, proj_W, proj_b,
                                        enc2, stdev, means, (float*)d_out);
}

// Round 18
// 564.652 us; speedup vs baseline: 1.1377x; 1.1377x over previous
//
#include <hip/hip_runtime.h>
#include <hip/hip_bf16.h>

#define NB 4
#define SEQ 512
#define CIN 21
#define TDIM 4
#define DM 256
#define NH 8
#define PLEN 16
#define PSTR 8
#define EL 63
#define DFF 1024
#define PRED 96
#define NT 260
#define EPSV 1e-5f

// ---------------- helpers --------------------------------------------------
template<int R, int N>
__device__ __forceinline__ void dot_rows(const float* sx, int stride, const float* w, float* acc) {
  const float4* w4 = reinterpret_cast<const float4*>(w);
  #pragma unroll 4
  for (int i = 0; i < N / 4; ++i) {
    float4 c = w4[i];
    #pragma unroll
    for (int r = 0; r < R; ++r) {
      const float4* x4 = reinterpret_cast<const float4*>(sx + r * stride + i * 4);
      float4 a = *x4;
      acc[r] += a.x*c.x + a.y*c.y + a.z*c.z + a.w*c.w;
    }
  }
}

__device__ __forceinline__ float red32(float v) {
  #pragma unroll
  for (int m = 1; m < 32; m <<= 1) v += __shfl_xor(v, m, 64);
  return v;
}
__device__ __forceinline__ float red32max(float v) {
  #pragma unroll
  for (int m = 1; m < 32; m <<= 1) v = fmaxf(v, __shfl_xor(v, m, 64));
  return v;
}

__device__ __forceinline__ float2 meanvar256(float v, float* sb) {
  __syncthreads();
  float s1 = v, s2 = v * v;
  #pragma unroll
  for (int off = 32; off > 0; off >>= 1) {
    s1 += __shfl_down(s1, off, 64);
    s2 += __shfl_down(s2, off, 64);
  }
  int wid = threadIdx.x >> 6, lane = threadIdx.x & 63;
  if (lane == 0) { sb[wid * 2] = s1; sb[wid * 2 + 1] = s2; }
  __syncthreads();
  float m = (sb[0] + sb[2] + sb[4] + sb[6]) * (1.0f / 256.0f);
  float q = (sb[1] + sb[3] + sb[5] + sb[7]) * (1.0f / 256.0f);
  return make_float2(m, q - m * m);
}

__device__ __forceinline__ void load16f(const float* p, float* o) {
  const float4* q = reinterpret_cast<const float4*>(p);
  float4 a = q[0], b = q[1], c = q[2], d = q[3];
  o[0]=a.x; o[1]=a.y; o[2]=a.z; o[3]=a.w;
  o[4]=b.x; o[5]=b.y; o[6]=b.z; o[7]=b.w;
  o[8]=c.x; o[9]=c.y; o[10]=c.z; o[11]=c.w;
  o[12]=d.x; o[13]=d.y; o[14]=d.z; o[15]=d.w;
}

__device__ __forceinline__ float dot32(const float4* a, const float4* b) {
  float s = 0.f;
  #pragma unroll
  for (int i = 0; i < 8; ++i) {
    float4 x = a[i], y = b[i];
    s += x.x*y.x + x.y*y.y + x.z*y.z + x.w*y.w;
  }
  return s;
}

// ---- K1: fused RevIN stats (84 blocks) + patch-time means (4 blocks) -----
__global__ void k_stats(const float* __restrict__ x, const float* __restrict__ xm,
                        float* __restrict__ means, float* __restrict__ stdev,
                        float* __restrict__ tout) {
  int blk = blockIdx.x;
  int t = threadIdx.x;
  if (blk < NB * CIN) {
    int b = blk / CIN, c = blk % CIN;
    const float* p = x + (size_t)b * SEQ * CIN + c;
    float v0 = p[t * CIN];
    float v1 = p[(t + 256) * CIN];
    float s1 = v0 + v1, s2 = v0 * v0 + v1 * v1;
    __shared__ float sb[8];
    #pragma unroll
    for (int off = 32; off > 0; off >>= 1) {
      s1 += __shfl_down(s1, off, 64);
      s2 += __shfl_down(s2, off, 64);
    }
    int wid = t >> 6, lane = t & 63;
    if (lane == 0) { sb[wid * 2] = s1; sb[wid * 2 + 1] = s2; }
    __syncthreads();
    if (t == 0) {
      float a = sb[0] + sb[2] + sb[4] + sb[6];
      float q = sb[1] + sb[3] + sb[5] + sb[7];
      float m = a * (1.0f / 512.0f);
      float var = q * (1.0f / 512.0f) - m * m;
      means[blk] = m;
      stdev[blk] = sqrtf(var + EPSV);
    }
  } else {
    int idx = (blk - NB * CIN) * 256 + t;
    if (idx >= NB * EL * TDIM) return;
    int b = idx / (EL * TDIM), r = idx % (EL * TDIM);
    int l = r >> 2, ti = r & 3;
    const float* p = xm + (size_t)b * SEQ * TDIM + (size_t)l * PSTR * TDIM + ti;
    float s = 0.f;
    #pragma unroll
    for (int k = 0; k < PLEN; ++k) s += p[k * TDIM];
    tout[idx] = s * (1.f / 16.f);
  }
}

// ---- K3a: token conv + PE, 8 positions per block -------------------------
__global__ void __launch_bounds__(256) k_tokconv(
    const float* __restrict__ x, const float* __restrict__ tokW,
    const float* __restrict__ means, const float* __restrict__ stdev,
    float* __restrict__ enc1) {
  int bi = blockIdx.x;                       // b*64 + sg
  int b = bi >> 6, sg = bi & 63;
  int s0 = sg * 8;
  __shared__ float sxr[10 * CIN];
  int t = threadIdx.x;
  if (t < 10 * CIN) {
    int li = t / CIN, c = t % CIN;
    int row = (s0 - 1 + li + SEQ) & 511;
    sxr[t] = (x[(size_t)b * SEQ * CIN + row * CIN + c] - means[b * CIN + c])
             / stdev[b * CIN + c];
  }
  __syncthreads();
  int d = t;
  float wreg[63];
  #pragma unroll
  for (int q = 0; q < 63; ++q) wreg[q] = tokW[d * 63 + q];
  int de = d & ~1;
  float dv = expf((float)de * (-9.210340371976184f / 256.0f));
  bool isodd = (d & 1);
  #pragma unroll 1
  for (int k = 0; k < 8; ++k) {
    float acc = 0.f;
    const float* sr = sxr + k * CIN;
    #pragma unroll
    for (int c = 0; c < CIN; ++c) {
      acc += sr[c]           * wreg[c * 3 + 0];
      acc += sr[CIN + c]     * wreg[c * 3 + 1];
      acc += sr[2 * CIN + c] * wreg[c * 3 + 2];
    }
    float ang = (float)(s0 + k) * dv;
    float pe = isodd ? cosf(ang) : sinf(ang);
    enc1[((size_t)b * SEQ + s0 + k) * DM + d] = acc + pe;
  }
}

// ---- K3b: patch conv partials, 6 patches x 32-channel chunk per block ----
__global__ void __launch_bounds__(256) k_patch_part(
    const float* __restrict__ enc1, const float* __restrict__ pW,
    float* __restrict__ pbuf) {
  int bi = blockIdx.x;
  int pg = bi >> 3, kc = bi & 7;
  int p0 = pg * 6;
  __shared__ __align__(16) float sA[6 * 32 * 20];
  int t = threadIdx.x;
  for (int idx = t; idx < 6 * 32 * PLEN; idx += 256) {
    int pp = idx >> 9;
    int rem = idx & 511;
    int c = rem >> 4, k = rem & 15;
    int p = p0 + pp;
    int b = p / EL, l = p % EL;
    sA[pp * 640 + c * 20 + k] =
        enc1[((size_t)b * SEQ + l * PSTR + k) * DM + kc * 32 + c];
  }
  __syncthreads();
  int d = t;
  const float4* w4 = reinterpret_cast<const float4*>(
      pW + (size_t)d * (DM * PLEN) + kc * 32 * PLEN);
  float acc[6] = {0.f, 0.f, 0.f, 0.f, 0.f, 0.f};
  #pragma unroll 2
  for (int c = 0; c < 32; ++c) {
    float4 w0 = w4[c*4+0], w1 = w4[c*4+1], w2 = w4[c*4+2], w3 = w4[c*4+3];
    #pragma unroll
    for (int pp = 0; pp < 6; ++pp) {
      const float4* px = reinterpret_cast<const float4*>(sA + pp * 640 + c * 20);
      float4 x0 = px[0], x1 = px[1], x2 = px[2], x3 = px[3];
      acc[pp] += x0.x*w0.x + x0.y*w0.y + x0.z*w0.z + x0.w*w0.w
               + x1.x*w1.x + x1.y*w1.y + x1.z*w1.z + x1.w*w1.w
               + x2.x*w2.x + x2.y*w2.y + x2.z*w2.z + x2.w*w2.w
               + x3.x*w3.x + x3.y*w3.y + x3.z*w3.z + x3.w*w3.w;
    }
  }
  const int S = NB * EL * DM;
  #pragma unroll
  for (int pp = 0; pp < 6; ++pp)
    pbuf[(size_t)kc * S + (size_t)(p0 + pp) * DM + d] = acc[pp];
}

// ---- K3c: reduce partials + bias -----------------------------------------
__global__ void k_patch_red(const float* __restrict__ pbuf, const float* __restrict__ pb,
                            float* __restrict__ encP) {
  int p = blockIdx.x, t = threadIdx.x;
  const int S = NB * EL * DM;
  float v = 0.f;
  #pragma unroll
  for (int s = 0; s < 8; ++s) v += pbuf[(size_t)s * S + (size_t)p * DM + t];
  encP[(size_t)p * DM + t] = v + pb[t];
}

// ---- QKV: one matrix per block, R rows, LDS-staged -----------------------
template<int R>
__global__ void __launch_bounds__(256) k_qkv1(
    const float* __restrict__ Wq, const float* __restrict__ Wk,
    const float* __restrict__ Wv,
    const float* __restrict__ bq, const float* __restrict__ bk,
    const float* __restrict__ bv,
    const float* __restrict__ xin,
    float* __restrict__ qo, float* __restrict__ ko, float* __restrict__ vo) {
  int bi = blockIdx.x;
  int rg = bi / 3, mat = bi % 3;
  int row0 = rg * R;
  __shared__ __align__(16) float sx[R * DM];
  int t = threadIdx.x;
  for (int idx = t; idx < R * DM; idx += 256) sx[idx] = xin[(size_t)row0 * DM + idx];
  __syncthreads();
  const float* W = (mat == 0) ? Wq : (mat == 1) ? Wk : Wv;
  const float* bias = (mat == 0) ? bq : (mat == 1) ? bk : bv;
  float* out = (mat == 0) ? qo : (mat == 1) ? ko : vo;
  float acc[R];
  #pragma unroll
  for (int r = 0; r < R; ++r) acc[r] = 0.f;
  dot_rows<R, DM>(sx, DM, W + (size_t)t * DM, acc);
  float bv_ = bias ? bias[t] : 0.f;
  #pragma unroll
  for (int r = 0; r < R; ++r) out[(size_t)(row0 + r) * DM + t] = acc[r] + bv_;
}

// ---- g_rel + g_abs(gi) precompute, BOTH layers in one launch -------------
__global__ void __launch_bounds__(256) k_grel2(
    const float* __restrict__ tws,
    const float* __restrict__ mu_r, const float* __restrict__ sg_r,
    const float* __restrict__ w_r,
    const float* __restrict__ mu_a, const float* __restrict__ sg_a,
    const float* __restrict__ w_a,
    float* __restrict__ grel, float* __restrict__ gib) {
  int blk = blockIdx.x;                      // L*(NB*252) + b*252 + chunk
  int L = blk / (NB * 252);
  int rem0 = blk % (NB * 252);
  int b = rem0 / 252, chunk = rem0 % 252;
  int po = L * 4096;
  float* grelL = grel + (size_t)L * (NB * NH * EL * EL);
  float* gibL  = gib + (size_t)L * (NB * NH * EL);
  int t = threadIdx.x;
  int h = t >> 5, dh = t & 31;
  __shared__ float s_t[EL * TDIM];
  if (t < EL * TDIM) s_t[t] = tws[b * EL * TDIM + t];
  float pm[16], pc[16], pw[16];
  load16f(mu_r + po + (size_t)t * 16, pm);
  load16f(sg_r + po + (size_t)t * 16, pc);
  load16f(w_r  + po + (size_t)t * 16, pw);
  #pragma unroll
  for (int p = 0; p < 16; ++p) pc[p] = -0.5f / (pc[p] * pc[p]);
  __syncthreads();
  #pragma unroll 1
  for (int q = 0; q < 8; ++q) {
    int p = chunk * 8 + q;                   // 2016 (i<=j) pairs
    int i = (int)((127.0f - sqrtf(16129.0f - 8.0f * (float)p)) * 0.5f);
    while (i * (127 - i) / 2 > p) --i;
    while ((i + 1) * (126 - i) / 2 <= p) ++i;
    int j = i + (p - i * (127 - i) / 2);
    float dvv[4];
    dvv[0] = fabsf(s_t[i*4+0] - s_t[j*4+0]);
    dvv[1] = fabsf(s_t[i*4+1] - s_t[j*4+1]);
    dvv[2] = fabsf(s_t[i*4+2] - s_t[j*4+2]);
    dvv[3] = fabsf(s_t[i*4+3] - s_t[j*4+3]);
    float srel = 0.f;
    #pragma unroll
    for (int tt = 0; tt < 4; ++tt)
      #pragma unroll
      for (int k = 0; k < 4; ++k) {
        int pp = tt * 4 + k;
        float df = dvv[tt] - pm[pp];
        srel += pw[pp] * __expf(pc[pp] * df * df);
      }
    #pragma unroll
    for (int m = 1; m < 32; m <<= 1) srel += __shfl_xor(srel, m, 64);
    if (dh == 0) {
      float v = srel * (1.f / 32.f);
      grelL[(((size_t)b * NH + h) * EL + i) * EL + j] = v;
      grelL[(((size_t)b * NH + h) * EL + j) * EL + i] = v;
    }
  }
  if (chunk < EL) {
    load16f(mu_a + po + (size_t)t * 16, pm);
    load16f(sg_a + po + (size_t)t * 16, pc);
    load16f(w_a  + po + (size_t)t * 16, pw);
    #pragma unroll
    for (int p = 0; p < 16; ++p) pc[p] = -0.5f / (pc[p] * pc[p]);
    int i = chunk;
    float tiv[4] = {s_t[i*4+0], s_t[i*4+1], s_t[i*4+2], s_t[i*4+3]};
    float sabs = 0.f;
    #pragma unroll
    for (int tt = 0; tt < 4; ++tt)
      #pragma unroll
      for (int k = 0; k < 4; ++k) {
        int pp = tt * 4 + k;
        float df = tiv[tt] - pm[pp];
        sabs += pw[pp] * __expf(pc[pp] * df * df);
      }
    #pragma unroll
    for (int m = 1; m < 32; m <<= 1) sabs += __shfl_xor(sabs, m, 64);
    if (dh == 0) gibL[((size_t)b * NH + h) * EL + i] = sabs * (1.f / 32.f);
  }
}

// ---- TKA attention: register-dot scores, no lane reductions --------------
__global__ void __launch_bounds__(256) k_tka_attn(
    const float* __restrict__ xin, const float* __restrict__ qw,
    const float* __restrict__ kw, const float* __restrict__ vw,
    const float* __restrict__ grel, const float* __restrict__ gib,
    const float* __restrict__ alpha, const float* __restrict__ beta,
    const float* __restrict__ gamma, float* __restrict__ ao) {
  int bi = blockIdx.x;                       // b*63+i
  int b = bi / EL, i = bi % EL;
  int t = threadIdx.x;
  int h = t >> 5, jj = t & 31;
  __shared__ __align__(16) float sQX[2 * DM];
  __shared__ float sP[NH * 64];
  if (t < DM) {
    sQX[t] = qw[(size_t)bi * DM + t];
    sQX[DM + t] = xin[(size_t)bi * DM + t];
  }
  __syncthreads();
  float gi = gib[((size_t)b * NH + h) * EL + i];
  float al = alpha[h], be = beta[h], ga = gamma[h];
  const float scale = 0.17677669529663687f;
  const float* grow = grel + (((size_t)b * NH + h) * EL + i) * EL;

  #pragma unroll
  for (int tile = 0; tile < 2; ++tile) {
    int j = tile * 32 + jj;
    bool valid = (j < EL);
    int jc = valid ? j : (EL - 1);
    const float4* kp = reinterpret_cast<const float4*>(
        kw + (size_t)(b * EL + jc) * DM + h * 32);
    const float4* xp = reinterpret_cast<const float4*>(
        xin + (size_t)(b * EL + jc) * DM + h * 32);
    float4 kf[8], xf[8];
    #pragma unroll
    for (int q = 0; q < 8; ++q) { kf[q] = kp[q]; xf[q] = xp[q]; }
    float qk  = dot32(reinterpret_cast<const float4*>(sQX + h * 32), kf);
    float pij = dot32(reinterpret_cast<const float4*>(sQX + DM + h * 32), xf);
    float A = al * pij * (2.f * gi) + be * pij * grow[jc] + ga;
    sP[h * 64 + tile * 32 + jj] = valid ? (qk * scale * A) : -1e30f;
  }
  __syncthreads();
  {
    int dh = jj;
    float v0 = sP[h * 64 + dh];
    float v1 = (dh + 32 < EL) ? sP[h * 64 + dh + 32] : -1e30f;
    float m = red32max(fmaxf(v0, v1));
    float e0 = __expf(v0 - m);
    float e1 = (dh + 32 < EL) ? __expf(v1 - m) : 0.f;
    float s = red32(e0 + e1);
    float inv = 1.f / s;
    sP[h * 64 + dh] = e0 * inv;
    if (dh + 32 < EL) sP[h * 64 + dh + 32] = e1 * inv;
  }
  __syncthreads();
  float acc = 0.f;
  for (int j = 0; j < EL; ++j)
    acc += sP[h * 64 + j] * vw[(size_t)(b * EL + j) * DM + t];
  ao[(size_t)bi * DM + t] = acc;
}

// ---- output projection (no LN), R rows, LDS-staged -----------------------
template<int R>
__global__ void k_oproj(const float* __restrict__ Wo, const float* __restrict__ bo,
                        const float* __restrict__ ain, float* __restrict__ out) {
  int row0 = blockIdx.x * R;
  __shared__ __align__(16) float sx[R * DM];
  int t = threadIdx.x;
  for (int idx = t; idx < R * DM; idx += 256) sx[idx] = ain[(size_t)row0 * DM + idx];
  __syncthreads();
  float acc[R];
  #pragma unroll
  for (int r = 0; r < R; ++r) acc[r] = 0.f;
  dot_rows<R, DM>(sx, DM, Wo + (size_t)t * DM, acc);
  float bias = bo[t];
  #pragma unroll
  for (int r = 0; r < R; ++r) out[(size_t)(row0 + r) * DM + t] = acc[r] + bias;
}

// ---- inverted embedding ----------------------------------------------------
__global__ void k_invemb(const float* __restrict__ invW, const float* __restrict__ invb,
                         const float* __restrict__ encP, const float* __restrict__ tws,
                         float* __restrict__ enc2) {
  int bi = blockIdx.x;                       // b*260+n
  int b = bi / NT, n = bi % NT;
  __shared__ float sx[EL];
  int t = threadIdx.x;
  if (t < EL) {
    sx[t] = (n < DM) ? encP[(size_t)(b * EL + t) * DM + n]
                     : tws[b * EL * TDIM + t * TDIM + (n - DM)];
  }
  __syncthreads();
  const float* w = invW + (size_t)t * EL;
  float acc = 0.f;
  for (int l = 0; l < EL; ++l) acc += sx[l] * w[l];
  enc2[(size_t)bi * DM + t] = acc + invb[t];
}

// ---- encoder attention: two-pass, full S in LDS --------------------------
__global__ void __launch_bounds__(256) k_enc_attn(
    const float* __restrict__ qw, const float* __restrict__ kw,
    const float* __restrict__ vw, float* __restrict__ ao) {
  int blk = blockIdx.x;                      // b*65 + tile
  int b = blk / 65, it = blk % 65;
  int i0 = it * 4;
  int t = threadIdx.x;
  int h = t >> 5, jj = t & 31;

  __shared__ __align__(16) float sQ[4 * DM];
  __shared__ float sS[4 * NH * NT];          // 33.3 KB
  __shared__ float sL[4 * NH];

  for (int idx = t; idx < 4 * DM; idx += 256)
    sQ[idx] = qw[((size_t)(b * NT + i0)) * DM + idx];
  __syncthreads();

  const float scale = 0.17677669529663687f;
  for (int tile = 0; tile < 9; ++tile) {
    int j = tile * 32 + jj;
    if (j >= NT) break;
    const float4* kp = reinterpret_cast<const float4*>(
        kw + ((size_t)(b * NT + j)) * DM + h * 32);
    float4 kf[8];
    #pragma unroll
    for (int q = 0; q < 8; ++q) kf[q] = kp[q];
    #pragma unroll
    for (int i = 0; i < 4; ++i) {
      float s = dot32(reinterpret_cast<const float4*>(sQ + i * DM + h * 32), kf);
      sS[(i * NH + h) * NT + j] = s * scale;
    }
  }
  __syncthreads();
  {
    int combo = t >> 3, lane8 = t & 7;
    float* row = sS + (size_t)combo * NT;
    float m = -1e30f;
    for (int jx = lane8; jx < NT; jx += 8) m = fmaxf(m, row[jx]);
    #pragma unroll
    for (int s8 = 1; s8 < 8; s8 <<= 1) m = fmaxf(m, __shfl_xor(m, s8, 64));
    float ssum = 0.f;
    for (int jx = lane8; jx < NT; jx += 8) {
      float e = __expf(row[jx] - m);
      row[jx] = e;
      ssum += e;
    }
    #pragma unroll
    for (int s8 = 1; s8 < 8; s8 <<= 1) ssum += __shfl_xor(ssum, s8, 64);
    if (lane8 == 0) sL[combo] = ssum;
  }
  __syncthreads();
  {
    int ch = t, hh = ch >> 5;
    float o0 = 0.f, o1 = 0.f, o2 = 0.f, o3 = 0.f;
    const float* vbase = vw + ((size_t)(b * NT)) * DM + ch;
    const float* p0 = sS + (0 * NH + hh) * NT;
    const float* p1 = sS + (1 * NH + hh) * NT;
    const float* p2 = sS + (2 * NH + hh) * NT;
    const float* p3 = sS + (3 * NH + hh) * NT;
    for (int j = 0; j < NT; ++j) {
      float v = vbase[(size_t)j * DM];
      o0 += p0[j] * v; o1 += p1[j] * v; o2 += p2[j] * v; o3 += p3[j] * v;
    }
    size_t obase = ((size_t)(b * NT + i0)) * DM + ch;
    ao[obase + 0 * DM] = o0 / sL[0 * NH + hh];
    ao[obase + 1 * DM] = o1 / sL[1 * NH + hh];
    ao[obase + 2 * DM] = o2 / sL[2 * NH + hh];
    ao[obase + 3 * DM] = o3 / sL[3 * NH + hh];
  }
}

// ---- Wo proj + residual + LN, 8 rows, LDS-staged -------------------------
__global__ void __launch_bounds__(256) k_oproj_res_ln(
    const float* __restrict__ Wo, const float* __restrict__ bo,
    const float* __restrict__ g, const float* __restrict__ bb,
    const float* __restrict__ ain, const float* __restrict__ resin,
    float* __restrict__ out) {
  int row0 = blockIdx.x * 8;
  __shared__ __align__(16) float sx[8 * DM];
  __shared__ float sb[8];
  int t = threadIdx.x;
  for (int idx = t; idx < 8 * DM; idx += 256) sx[idx] = ain[(size_t)row0 * DM + idx];
  __syncthreads();
  float acc[8];
  #pragma unroll
  for (int r = 0; r < 8; ++r) acc[r] = 0.f;
  dot_rows<8, DM>(sx, DM, Wo + (size_t)t * DM, acc);
  float bias = bo[t], gg = g[t], bb2 = bb[t];
  #pragma unroll 1
  for (int r = 0; r < 8; ++r) {
    float o = acc[r] + bias + resin[(size_t)(row0 + r) * DM + t];
    float2 mv = meanvar256(o, sb);
    out[(size_t)(row0 + r) * DM + t] = (o - mv.x) * rsqrtf(mv.y + EPSV) * gg + bb2;
  }
}

// ---- FFN1: gelu(x@W1.T+b1), 8 rows x 256 f per block ---------------------
__global__ void __launch_bounds__(256) k_ffn1(
    const float* __restrict__ W1, const float* __restrict__ b1,
    const float* __restrict__ xn, float* __restrict__ y1) {
  int bi = blockIdx.x;                       // rg*4 + fg
  int rg = bi >> 2, fg = bi & 3;
  int row0 = rg * 8;
  __shared__ __align__(16) float sx[8 * DM];
  int t = threadIdx.x;
  for (int idx = t; idx < 8 * DM; idx += 256) sx[idx] = xn[(size_t)row0 * DM + idx];
  __syncthreads();
  int f = fg * 256 + t;
  float acc[8];
  #pragma unroll
  for (int r = 0; r < 8; ++r) acc[r] = 0.f;
  dot_rows<8, DM>(sx, DM, W1 + (size_t)f * DM, acc);
  float bias = b1[f];
  #pragma unroll
  for (int r = 0; r < 8; ++r) {
    float a = acc[r] + bias;
    y1[(size_t)(row0 + r) * DFF + f] = 0.5f * a * (1.f + erff(a * 0.70710678118654752f));
  }
}

// ---- FFN2 partials: 8 rows x 256-K chunk per block -----------------------
__global__ void __launch_bounds__(256) k_ffn2_part(
    const float* __restrict__ W2, const float* __restrict__ y1,
    float* __restrict__ fbuf) {
  int bi = blockIdx.x;                       // rg*4 + kc
  int rg = bi >> 2, kc = bi & 3;
  int row0 = rg * 8;
  __shared__ __align__(16) float sy[8 * 256];
  int t = threadIdx.x;
  for (int idx = t; idx < 8 * 256; idx += 256) {
    int r = idx >> 8, k = idx & 255;
    sy[idx] = y1[(size_t)(row0 + r) * DFF + kc * 256 + k];
  }
  __syncthreads();
  float acc[8];
  #pragma unroll
  for (int r = 0; r < 8; ++r) acc[r] = 0.f;
  dot_rows<8, 256>(sy, 256, W2 + (size_t)t * DFF + kc * 256, acc);
  const size_t S = (size_t)NB * NT * DM;
  #pragma unroll
  for (int r = 0; r < 8; ++r)
    fbuf[(size_t)kc * S + (size_t)(row0 + r) * DM + t] = acc[r];
}

// ---- FFN2 reduce + bias + residual + LN, 4 rows --------------------------
__global__ void __launch_bounds__(256) k_ffn2_red(
    const float* __restrict__ fbuf, const float* __restrict__ b2,
    const float* __restrict__ g, const float* __restrict__ bb,
    const float* __restrict__ xn, float* __restrict__ out) {
  int row0 = blockIdx.x * 4;
  __shared__ float sb[8];
  int t = threadIdx.x;
  const size_t S = (size_t)NB * NT * DM;
  float bi_ = b2[t], gg = g[t], bb2 = bb[t];
  #pragma unroll 1
  for (int r = 0; r < 4; ++r) {
    size_t off = (size_t)(row0 + r) * DM + t;
    float o = fbuf[off] + fbuf[S + off] + fbuf[2 * S + off] + fbuf[3 * S + off]
            + bi_ + xn[off];
    float2 mv = meanvar256(o, sb);
    out[off] = (o - mv.x) * rsqrtf(mv.y + EPSV) * gg + bb2;
  }
}

// ---- final LN + projection + denorm (fp32 output) ------------------------
__global__ void k_final(const float* __restrict__ g, const float* __restrict__ bb,
                        const float* __restrict__ pW, const float* __restrict__ pb,
                        const float* __restrict__ enc2,
                        const float* __restrict__ stdev, const float* __restrict__ means,
                        float* __restrict__ out) {
  int bi = blockIdx.x;                       // b*21+c
  int b = bi / CIN, c = bi % CIN;
  __shared__ __align__(16) float sx[DM];
  __shared__ float sb[8];
  int t = threadIdx.x;
  float v = enc2[(size_t)(b * NT + c) * DM + t];
  float2 mv = meanvar256(v, sb);
  sx[t] = (v - mv.x) * rsqrtf(mv.y + EPSV) * g[t] + bb[t];
  __syncthreads();
  if (t < PRED) {
    float acc[1] = {0.f};
    dot_rows<1, DM>(sx, DM, pW + (size_t)t * DM, acc);
    float y = (acc[0] + pb[t]) * stdev[bi] + means[bi];
    out[(size_t)b * PRED * CIN + t * CIN + c] = y;
  }
}

extern "C" void kernel_launch(void* const* d_in, const int* in_sizes, int n_in,
                              void* d_out, int out_size, void* d_ws, size_t ws_size,
                              hipStream_t stream) {
  const float* x_enc   = (const float*)d_in[0];
  const float* x_mark  = (const float*)d_in[1];
  const float* tok_W   = (const float*)d_in[4];
  const float* patch_W = (const float*)d_in[5];
  const float* patch_b = (const float*)d_in[6];
  const float* nl_WQ   = (const float*)d_in[7];
  const float* nl_WK   = (const float*)d_in[8];
  const float* nl_WV   = (const float*)d_in[9];
  const float* nl_WO   = (const float*)d_in[10];
  const float* nl_bO   = (const float*)d_in[11];
  const float* nl_mu_a = (const float*)d_in[12];
  const float* nl_sg_a = (const float*)d_in[13];
  const float* nl_w_a  = (const float*)d_in[14];
  const float* nl_mu_r = (const float*)d_in[15];
  const float* nl_sg_r = (const float*)d_in[16];
  const float* nl_w_r  = (const float*)d_in[17];
  const float* nl_al   = (const float*)d_in[18];
  const float* nl_be   = (const float*)d_in[19];
  const float* nl_ga   = (const float*)d_in[20];
  const float* inv_W   = (const float*)d_in[21];
  const float* inv_b   = (const float*)d_in[22];
  const float* el_Wq   = (const float*)d_in[23];
  const float* el_bq   = (const float*)d_in[24];
  const float* el_Wk   = (const float*)d_in[25];
  const float* el_bk   = (const float*)d_in[26];
  const float* el_Wv   = (const float*)d_in[27];
  const float* el_bv   = (const float*)d_in[28];
  const float* el_Wo   = (const float*)d_in[29];
  const float* el_bo   = (const float*)d_in[30];
  const float* el_W1   = (const float*)d_in[31];
  const float* el_b1   = (const float*)d_in[32];
  const float* el_W2   = (const float*)d_in[33];
  const float* el_b2   = (const float*)d_in[34];
  const float* n1g     = (const float*)d_in[35];
  const float* n1b     = (const float*)d_in[36];
  const float* n2g     = (const float*)d_in[37];
  const float* n2b     = (const float*)d_in[38];
  const float* norm_g  = (const float*)d_in[39];
  const float* norm_b  = (const float*)d_in[40];
  const float* proj_W  = (const float*)d_in[41];
  const float* proj_b  = (const float*)d_in[42];

  // workspace layout (floats): ~19.3 MB
  float* ws = (float*)d_ws;
  float* means = ws + 0;          //     96
  float* stdev = ws + 96;         //     96
  float* tws   = ws + 192;        //   1024
  float* enc1  = ws + 1216;       // 524288  (B,512,256)
  float* encP  = ws + 525504;     //  64512  (252,256)
  float* pbuf  = ws + 590016;     // 516096  (8,252,256)
  float* enc2  = ws + 1106112;    // 266240  (1040,256)
  float* ao    = ws + 1372352;    // 266240
  float* qb    = ws + 1638592;    // 266240  (xn aliases qb)
  float* kb    = ws + 1904832;    // 266240
  float* vb    = ws + 2171072;    // 266240
  float* y1    = ws + 2437312;    // 1064960 (1040,1024)
  float* fbuf  = ws + 3502272;    // 1064960 (4,1040,256)
  float* grel  = ws + 4567232;    // 254016  (2,B,8,63,63)
  float* gib   = ws + 4821248;    //   4032  (2,B,8,63)
  float* xn    = qb;              // alias: qb dead after k_enc_attn

  k_stats<<<NB * CIN + 4, 256, 0, stream>>>(x_enc, x_mark, means, stdev, tws);
  k_tokconv<<<NB * 64, 256, 0, stream>>>(x_enc, tok_W, means, stdev, enc1);
  k_grel2<<<2 * NB * 252, 256, 0, stream>>>(tws, nl_mu_r, nl_sg_r, nl_w_r,
                                            nl_mu_a, nl_sg_a, nl_w_a, grel, gib);
  k_patch_part<<<42 * 8, 256, 0, stream>>>(enc1, patch_W, pbuf);
  k_patch_red<<<NB * EL, 256, 0, stream>>>(pbuf, patch_b, encP);

  for (int L = 0; L < 2; ++L) {
    size_t wo = (size_t)L * DM * DM;
    k_qkv1<4><<<63 * 3, 256, 0, stream>>>(nl_WQ + wo, nl_WK + wo, nl_WV + wo,
                                          nullptr, nullptr, nullptr,
                                          encP, qb, kb, vb);
    k_tka_attn<<<NB * EL, 256, 0, stream>>>(encP, qb, kb, vb,
        grel + (size_t)L * (NB * NH * EL * EL), gib + (size_t)L * (NB * NH * EL),
        nl_al + L * 8, nl_be + L * 8, nl_ga + L * 8, ao);
    k_oproj<2><<<NB * EL / 2, 256, 0, stream>>>(nl_WO + wo, nl_bO + L * DM, ao, encP);
  }

  k_invemb<<<NB * NT, 256, 0, stream>>>(inv_W, inv_b, encP, tws, enc2);

  for (int L = 0; L < 2; ++L) {
    size_t wo = (size_t)L * DM * DM;
    size_t bo = (size_t)L * DM;
    size_t fo = (size_t)L * DFF * DM;
    k_qkv1<8><<<130 * 3, 256, 0, stream>>>(el_Wq + wo, el_Wk + wo, el_Wv + wo,
                                           el_bq + bo, el_bk + bo, el_bv + bo,
                                           enc2, qb, kb, vb);
    k_enc_attn<<<NB * 65, 256, 0, stream>>>(qb, kb, vb, ao);
    k_oproj_res_ln<<<NB * NT / 8, 256, 0, stream>>>(el_Wo + wo, el_bo + bo,
                                                    n1g + bo, n1b + bo,
                                                    ao, enc2, xn);
    k_ffn1<<<130 * 4, 256, 0, stream>>>(el_W1 + fo, el_b1 + L * DFF, xn, y1);
    k_ffn2_part<<<130 * 4, 256, 0, stream>>>(el_W2 + fo, y1, fbuf);
    k_ffn2_red<<<NB * NT / 4, 256, 0, stream>>>(fbuf, el_b2 + bo,
                                                n2g + bo, n2b + bo, xn, enc2);
  }

  k_final<<<NB * CIN, 256, 0, stream>>>(norm_g, norm_b, proj_W, proj_b,
                                        enc2, stdev, means, (float*)d_out);
}